// Round 12
// baseline (202.338 us; speedup 1.0000x reference)
//
#include <hip/hip_runtime.h>

// Correlation / cost-volume, fp32.
// corr[b, dy*9+dx, y, x] = (1/128) * sum_c in1[b,c,y,x] * in2[b,c,y+dy-4,x+dx-4]
//
// R19: fully-consumed L1 lines. Evidence: R17 (barrier) 84.0 us beats
// R18 (no barrier) 90.2 us with FETCH 65.5->69 MB => barrier retained
// (drift thrashes 32KB L1). Remaining stall (both ~35% VALUBusy, wall
// 1575 cyc/chunk vs ~460 issue): old layout loaded 32 B/lane at 32 B
// stride -> every dwordx4 touches 8 lines per row-group for 32 B each
// => 128 half-consumed L1 line-accesses/wave/chunk (~1152 cyc/chunk/CU
// at 1 line/cyc, 9 waves) ~= the measured wall. Fix: split-row layout.
// Thread owns px 4xg..4xg+3 (low half of row) + 64+4xg..64+4xg+3 (high
// half); all loads/stores are 16-lane contiguous float4 -> lines fully
// consumed -> 64 line-accesses/wave/chunk (2x cut). Seam at px 63/64
// crossed via DPP row_ror wraps + cndmask (only lanes 0/15 differ):
//   WL[8+j]: lane15 needs wh[0] -> ror:15 (lane i <- lane (i+1)%16)
//   WH[j]:   lane0  needs wl[15] -> ror:1  (lane i <- lane (i-1)%16)
// (+16 DPP +8 cndmask per chunk ~ +12% VALU; FMA/bytes/regs unchanged.)
// Geometry/pipeline identical to R17: NT=576 zero-dead-lane, TY=4,
// grid 256 = 1 block/CU, depth-2 register pipeline, pacing s_barrier
// every 2 chunks, launch_bounds(576,1).

#define MAXD 4
#define ND 9
#define NDISP 81
#define BATCH 8
#define CH 128
#define HH 128
#define WW 128
#define HW (HH * WW)
#define NCHUNK CH                 // 1 channel per pipeline stage
#define TY 4
#define NT 576                    // 9 waves; every lane computes

// validated: row_shr:1 (0x111) = lane i <- lane i-1 (lane0 -> 0)
//            row_shl:1 (0x101) = lane i <- lane i+1 (lane15 -> 0)
// derived:   row_ror:1 (0x121) = lane i <- lane (i-1)%16 (lane0 <- lane15)
//            row_ror:15(0x12F) = lane i <- lane (i+1)%16 (lane15 <- lane0)
__device__ __forceinline__ float dpp_shr1(float x) {
    return __int_as_float(__builtin_amdgcn_update_dpp(
        0, __float_as_int(x), 0x111, 0xF, 0xF, true));
}
__device__ __forceinline__ float dpp_shl1(float x) {
    return __int_as_float(__builtin_amdgcn_update_dpp(
        0, __float_as_int(x), 0x101, 0xF, 0xF, true));
}
__device__ __forceinline__ float dpp_ror1(float x) {
    return __int_as_float(__builtin_amdgcn_update_dpp(
        0, __float_as_int(x), 0x121, 0xF, 0xF, true));
}
__device__ __forceinline__ float dpp_ror15(float x) {
    return __int_as_float(__builtin_amdgcn_update_dpp(
        0, __float_as_int(x), 0x12F, 0xF, 0xF, true));
}

__global__ __launch_bounds__(NT, 1) void corr_kernel(
    const float* __restrict__ in1,
    const float* __restrict__ in2,
    float* __restrict__ out)
{
    const int tid = threadIdx.x;
    const int b   = blockIdx.x;
    const int y0  = blockIdx.y * TY;
    const int xg  = tid & 15;               // 16 lanes; thread owns px 4xg+i, 64+4xg+i
    const int dy  = (tid >> 4) % ND;        // 9 dy groups
    const int ly  = tid / 144;              // 0..3: row within tile
    const int rl  = ly + dy;                // in2 row offset consumed (0..11)
    const bool rok = (unsigned)(y0 + rl - MAXD) < (unsigned)HH;
    int r2 = y0 + rl - MAXD;                // clamped row; garbage zeroed at end
    r2 = r2 < 0 ? 0 : (r2 > HH - 1 ? HH - 1 : r2);

    const float* p2 = in2 + (size_t)b * CH * HW + (size_t)r2 * WW + 4 * xg;
    const float* p1 = in1 + (size_t)b * CH * HW + (size_t)(y0 + ly) * WW + 4 * xg;

    const bool is15 = (xg == 15);
    const bool is0  = (xg == 0);

    float accL[ND][4], accH[ND][4];
    #pragma unroll
    for (int d = 0; d < ND; ++d)
        #pragma unroll
        for (int i = 0; i < 4; ++i) { accL[d][i] = 0.0f; accH[d][i] = 0.0f; }

    // 2 named pipeline stages (static indexing only -> registers)
    float wl0[4], wh0[4], al0[4], ah0[4];
    float wl1[4], wh1[4], al1[4], ah1[4];

    // load chunk: 4 fully-contiguous float4 instrs (wl, wh, al, ah)
    auto LD = [&](float* wl, float* wh, float* al, float* ah) {
        float4 t0 = *(const float4*)(p2);        // in2 row px 4xg..4xg+3
        float4 t1 = *(const float4*)(p2 + 64);   // in2 row px 64+4xg..
        float4 u0 = *(const float4*)(p1);        // in1 row px 4xg..
        float4 u1 = *(const float4*)(p1 + 64);   // in1 row px 64+4xg..
        wl[0]=t0.x; wl[1]=t0.y; wl[2]=t0.z; wl[3]=t0.w;
        wh[0]=t1.x; wh[1]=t1.y; wh[2]=t1.z; wh[3]=t1.w;
        al[0]=u0.x; al[1]=u0.y; al[2]=u0.z; al[3]=u0.w;
        ah[0]=u1.x; ah[1]=u1.y; ah[2]=u1.z; ah[3]=u1.w;
        p2 += HW; p1 += HW;
    };

    auto CMP = [&](const float* wl, const float* wh,
                   const float* al, const float* ah) {
        float WL[12], WH[12];
        #pragma unroll
        for (int j = 0; j < 4; ++j) {
            WL[j]     = dpp_shr1(wl[j]);             // px 4xg-4+j; lane0 -> 0 pad
            WL[4 + j] = wl[j];                       // px 4xg+j
            float tl  = dpp_shl1(wl[j]);             // px 4xg+4+j (lane15 -> 0)
            float twr = dpp_ror15(wh[j]);            // lane15 <- wh[0] = px 64+j
            WL[8 + j] = is15 ? twr : tl;
            float ts  = dpp_shr1(wh[j]);             // px 64+4xg-4+j (lane0 -> 0)
            float trl = dpp_ror1(wl[j]);             // lane0 <- wl[15] = px 60+j
            WH[j]     = is0 ? trl : ts;
            WH[4 + j] = wh[j];                       // px 64+4xg+j
            WH[8 + j] = dpp_shl1(wh[j]);             // px 64+4xg+4+j; lane15 -> 0 pad
        }
        #pragma unroll
        for (int d = 0; d < ND; ++d)
            #pragma unroll
            for (int i = 0; i < 4; ++i) {
                accL[d][i] = fmaf(al[i], WL[i + d], accL[d][i]);
                accH[d][i] = fmaf(ah[i], WH[i + d], accH[d][i]);
            }
    };

    // ---- depth-2 software pipeline, pacing barrier every 2 chunks ----
    LD(wl0, wh0, al0, ah0);                               // chunk 0
    #pragma unroll 1
    for (int k = 0; k < NCHUNK; k += 2) {
        LD(wl1, wh1, al1, ah1);                           // chunk k+1
        CMP(wl0, wh0, al0, ah0);                          // chunk k
        if (k + 2 < NCHUNK) LD(wl0, wh0, al0, ah0);       // chunk k+2
        CMP(wl1, wh1, al1, ah1);                          // chunk k+1
        // pacing only: no waitcnt, no memory clobber, uniform control flow.
        // R17 vs R18 A/B: keeps block working set tight in L1 (84 vs 90 us).
        asm volatile("s_barrier");
    }

    // ---- epilogue: mean over C; OOB in2 rows scale to exact zero ----
    const float sc = rok ? (1.0f / (float)CH) : 0.0f;
    float* outrow = out + (size_t)b * NDISP * HW + (size_t)(y0 + ly) * WW;
    #pragma unroll
    for (int d = 0; d < ND; ++d) {
        float* op = outrow + (size_t)(dy * ND + d) * HW + 4 * xg;
        *(float4*)(op)      = make_float4(accL[d][0] * sc, accL[d][1] * sc,
                                          accL[d][2] * sc, accL[d][3] * sc);
        *(float4*)(op + 64) = make_float4(accH[d][0] * sc, accH[d][1] * sc,
                                          accH[d][2] * sc, accH[d][3] * sc);
    }
}

extern "C" void kernel_launch(void* const* d_in, const int* in_sizes, int n_in,
                              void* d_out, int out_size, void* d_ws, size_t ws_size,
                              hipStream_t stream) {
    const float* in1 = (const float*)d_in[0];
    const float* in2 = (const float*)d_in[1];
    float* out = (float*)d_out;
    dim3 grid(BATCH, HH / TY);
    corr_kernel<<<grid, NT, 0, stream>>>(in1, in2, out);
}